// Round 3
// baseline (744.543 us; speedup 1.0000x reference)
//
#include <hip/hip_runtime.h>
#include <hip/hip_bf16.h>

typedef __attribute__((ext_vector_type(8))) short bf16x8;
typedef __attribute__((ext_vector_type(4))) float f32x4;

#define NB 8
#define C1 256
#define HH 192
#define WW 192
#define GH 48
#define GW 48
#define NP 2304
#define KSEL 576
#define RH 64
#define HID 128
#define C4 1024
#define HW (HH*WW)

// ---- workspace layout (byte offsets) ----
#define WS_FLAG 0
#define WS_F 64
#define WS_W16 81280ull
#define WS_POOLED 605696ull
#define WS_PSCALE WS_POOLED   /* pooled dead after k_mlp; reuse for pscale */
#define WS_SCORES 19480064ull

// ---- float-index offsets inside F section ----
#define F_RW1 0
#define F_RG1 16384
#define F_RB1 16448
#define F_RW2 16512
#define F_RBIAS2 16576
#define F_EG1 16580
#define F_EB1 16708
#define F_DWW 16836
#define F_DWG 17988
#define F_DWB 18116
#define F_EG2 18244
#define F_EB2 19268

__device__ __forceinline__ float b2f(unsigned short h) {
  return __uint_as_float(((unsigned)h) << 16);
}
__device__ __forceinline__ unsigned short f2b(float f) {
  unsigned u = __float_as_uint(f);
  u += 0x7FFF + ((u >> 16) & 1u);
  return (unsigned short)(u >> 16);
}
__device__ __forceinline__ float siluf(float v) { return v / (1.f + expf(-v)); }

// ---- dtype detector ----
__global__ void k_detect(const unsigned short* xb, char* ws) {
  __shared__ int cnt[256];
  int t = threadIdx.x;
  int c = 0;
  for (int s = 0; s < 32; ++s) {
    unsigned short u = xb[(t * 32 + s) * 2];
    int e = (u >> 7) & 0xFF;
    c += (u == 0 || (e >= 90 && e <= 145)) ? 1 : 0;
  }
  cnt[t] = c;
  __syncthreads();
  for (int s = 128; s > 0; s >>= 1) {
    if (t < s) cnt[t] += cnt[t + s];
    __syncthreads();
  }
  if (t == 0) *(int*)(ws + WS_FLAG) = (cnt[0] >= 4915) ? 1 : 0;
}

// ---- weight prep: fp32 params into F, expert 1x1 weights into bf16 ----
__global__ void k_prep(const void* rw1, const void* rg1, const void* rb1, const void* rw2,
                       const void* rbias2, const void* ew1, const void* eg1, const void* eb1,
                       const void* dww, const void* dwg, const void* dwb, const void* ew2,
                       const void* eg2, const void* eb2, char* ws) {
  int bf = *(const int*)(ws + WS_FLAG);
  float* F = (float*)(ws + WS_F);
  unsigned short* W16 = (unsigned short*)(ws + WS_W16);
  int i = blockIdx.x * 256 + threadIdx.x;
  if (i >= 282433) return;
  if (i < 20289) {  // fp32 section
    const void* src; int si; int dof;
    if      (i < 16384) { src = rw1;    si = i;          dof = F_RW1 + si; }
    else if (i < 16448) { src = rg1;    si = i - 16384;  dof = F_RG1 + si; }
    else if (i < 16512) { src = rb1;    si = i - 16448;  dof = F_RB1 + si; }
    else if (i < 16576) { src = rw2;    si = i - 16512;  dof = F_RW2 + si; }
    else if (i < 16577) { src = rbias2; si = i - 16576;  dof = F_RBIAS2 + si; }
    else if (i < 16705) { src = eg1;    si = i - 16577;  dof = F_EG1 + si; }
    else if (i < 16833) { src = eb1;    si = i - 16705;  dof = F_EB1 + si; }
    else if (i < 17985) { src = dww;    si = i - 16833;  dof = F_DWW + si; }
    else if (i < 18113) { src = dwg;    si = i - 17985;  dof = F_DWG + si; }
    else if (i < 18241) { src = dwb;    si = i - 18113;  dof = F_DWB + si; }
    else if (i < 19265) { src = eg2;    si = i - 18241;  dof = F_EG2 + si; }
    else                { src = eb2;    si = i - 19265;  dof = F_EB2 + si; }
    F[dof] = bf ? b2f(((const unsigned short*)src)[si]) : ((const float*)src)[si];
  } else {          // bf16 weight section: W1b then W2b
    int j = i - 20289;
    const void* src; int si; int dof;
    if (j < 131072) { src = ew1; si = j;          dof = j; }
    else            { src = ew2; si = j - 131072; dof = j; }
    W16[dof] = bf ? ((const unsigned short*)src)[si]
                  : f2b(((const float*)src)[si]);
  }
}

// ---- 4x4 avg pool (order-preserving vs rounds 1-2 -> identical selection) ----
template<int BF>
__global__ void k_pool(const void* xin, char* ws) {
  if ((*(const int*)(ws + WS_FLAG) != 0) != (BF != 0)) return;
  float* pooled = (float*)(ws + WS_POOLED);
  int tid = blockIdx.x * 256 + threadIdx.x;
  int px = tid % GW;
  int t2 = tid / GW;
  int py = t2 % GH;
  int bc = t2 / GH;
  size_t base = (size_t)bc * HW + (size_t)(py * 4) * WW + px * 4;
  float s = 0.f;
#pragma unroll
  for (int r = 0; r < 4; ++r) {
    if (BF) {
      const ushort4 v = *(const ushort4*)((const unsigned short*)xin + base + r * WW);
      s += b2f(v.x) + b2f(v.y) + b2f(v.z) + b2f(v.w);
    } else {
      const float4 v = *(const float4*)((const float*)xin + base + r * WW);
      s += v.x + v.y + v.z + v.w;
    }
  }
  pooled[tid] = s * 0.0625f;
}

// ---- router MLP: 4 threads per position, each 16 hidden units ----
__global__ void k_mlp(char* ws) {
  const float* F = (const float*)(ws + WS_F);
  const float* pooled = (const float*)(ws + WS_POOLED);
  float* scores = (float*)(ws + WS_SCORES);
  int gid = blockIdx.x * 256 + threadIdx.x;   // 288 blocks -> 73728 threads
  int pos = gid >> 2, q = gid & 3;
  int b = pos / NP, pp = pos - b * NP;
  const float* pb = pooled + (size_t)b * C1 * NP + pp;
  const float* wr0 = F + F_RW1 + (q * 16) * C1;
  float acc[16];
#pragma unroll
  for (int j = 0; j < 16; ++j) acc[j] = 0.f;
  for (int c = 0; c < C1; ++c) {
    float pv = pb[(size_t)c * NP];
#pragma unroll
    for (int j = 0; j < 16; ++j) acc[j] += wr0[j * C1 + c] * pv;
  }
  const float BNS = 1.f / sqrtf(1.f + 1e-5f);
  float lp = 0.f;
#pragma unroll
  for (int j = 0; j < 16; ++j) {
    int h = q * 16 + j;
    float v = acc[j] * (F[F_RG1 + h] * BNS) + F[F_RB1 + h];
    lp += F[F_RW2 + h] * siluf(v);
  }
  lp += __shfl_xor(lp, 1, 64);
  lp += __shfl_xor(lp, 2, 64);
  if (q == 0) scores[pos] = 1.f / (1.f + expf(-(lp + F[F_RBIAS2])));
}

// ---- per-patch scale: score if in top-k else 0 ----
__global__ void k_route(char* ws) {
  const float* scores = (const float*)(ws + WS_SCORES);
  float* pscale = (float*)(ws + WS_PSCALE);
  int b = blockIdx.x / 9, r = blockIdx.x % 9;
  __shared__ float s[NP];
  for (int i = threadIdx.x; i < NP; i += 256) s[i] = scores[b * NP + i];
  __syncthreads();
  int i = r * 256 + threadIdx.x;
  float si = s[i];
  int rank = 0;
  for (int j = 0; j < NP; ++j) {
    float sj = s[j];
    rank += (sj > si || (sj == si && j < i)) ? 1 : 0;
  }
  pscale[b * NP + i] = (rank < KSEL) ? si : 0.f;
}

// ======================= dense expert =======================
// n-labeling: n = pix*16 + patch  (pix = pr*2+pc within 2x2, patch = 0..15)

#define XLOAD(P_, cc_) do { \
    size_t o_ = (size_t)(cc_) * 16 * HW; \
    if (BF) { P_##h0 = *(const ushort4*)(xh + xoff0 + o_); \
              P_##h1 = *(const ushort4*)(xh + xoff1 + o_); } \
    else    { P_##f0 = *(const float4*)(xf + xoff0 + o_); \
              P_##f1 = *(const float4*)(xf + xoff1 + o_); } \
    const unsigned short* wp_ = W1b + (cc_) * 64; \
    P_##w0 = *(const uint4*)(wp_ + wi0); \
    P_##w1 = *(const uint4*)(wp_ + wi1); \
  } while(0)

#define XWRITE(P_, UT_, WC_) do { \
    unsigned lo0_, hi0_, lo1_, hi1_; \
    if (BF) { lo0_ = P_##h0.x | ((unsigned)P_##h0.y << 16); hi0_ = P_##h0.z | ((unsigned)P_##h0.w << 16); \
              lo1_ = P_##h1.x | ((unsigned)P_##h1.y << 16); hi1_ = P_##h1.z | ((unsigned)P_##h1.w << 16); } \
    else    { lo0_ = f2b(P_##f0.x) | ((unsigned)f2b(P_##f0.y) << 16); hi0_ = f2b(P_##f0.z) | ((unsigned)f2b(P_##f0.w) << 16); \
              lo1_ = f2b(P_##f1.x) | ((unsigned)f2b(P_##f1.y) << 16); hi1_ = f2b(P_##f1.z) | ((unsigned)f2b(P_##f1.w) << 16); } \
    *(unsigned*)&UT_[n_lo72 + kb0] = lo0_; \
    *(unsigned*)&UT_[n_hi72 + kb0] = hi0_; \
    *(unsigned*)&UT_[n_lo72 + kb1] = lo1_; \
    *(unsigned*)&UT_[n_hi72 + kb1] = hi1_; \
    *(uint4*)&WC_[wcw0] = P_##w0; \
    *(uint4*)&WC_[wcw1] = P_##w1; \
  } while(0)

#define MFMA1(WCO_, B_, ACC_) ACC_ = __builtin_amdgcn_mfma_f32_16x16x32_bf16(*(const bf16x8*)&WC_[wc_off + (WCO_)], B_, ACC_, 0, 0, 0)

#define G1_MFMA(UT_, WCp_) do { \
    const unsigned short* WC_ = WCp_; \
    bf16x8 b0_ = *(const bf16x8*)&UT_[ut_off]; \
    bf16x8 b1_ = *(const bf16x8*)&UT_[ut_off + 32]; \
    MFMA1(0, b0_, acc10);    MFMA1(1152, b0_, acc11); \
    MFMA1(2304, b0_, acc12); MFMA1(3456, b0_, acc13); \
    MFMA1(32, b1_, acc10);   MFMA1(1152+32, b1_, acc11); \
    MFMA1(2304+32, b1_, acc12); MFMA1(3456+32, b1_, acc13); \
  } while(0)

#define G1EPI(ACC_, mi_) do { \
    _Pragma("unroll") \
    for (int r_ = 0; r_ < 4; ++r_) { \
      int h_ = 64 * wm + 16 * (mi_) + l4 * 4 + r_; \
      O1[h_ * 68 + otc] = siluf(ACC_[r_] * (F[F_EG1 + h_] * BNS) + F[F_EB1 + h_]); \
    } \
  } while(0)

#define G2_STEP(P_, WCp_, mt_) do { \
    const unsigned short* WC_ = WCp_; \
    *(uint4*)&((unsigned short*)WCp_)[w2a] = P_##a; \
    *(uint4*)&((unsigned short*)WCp_)[w2b] = P_##b; \
    if ((mt_) < 14) { \
      const unsigned short* wp_ = W2b + (size_t)((mt_) + 2) * 8192; \
      P_##a = *(const uint4*)(wp_ + w2s); \
      P_##b = *(const uint4*)(wp_ + w2s + 64); \
    } \
    __syncthreads(); \
    f32x4 a20 = (f32x4){0.f, 0.f, 0.f, 0.f}; \
    f32x4 a21 = (f32x4){0.f, 0.f, 0.f, 0.f}; \
    a20 = __builtin_amdgcn_mfma_f32_16x16x32_bf16(*(const bf16x8*)&WC_[g2_off + 0],        bq0, a20, 0,0,0); \
    a21 = __builtin_amdgcn_mfma_f32_16x16x32_bf16(*(const bf16x8*)&WC_[g2_off + 2176],     bq0, a21, 0,0,0); \
    a20 = __builtin_amdgcn_mfma_f32_16x16x32_bf16(*(const bf16x8*)&WC_[g2_off + 32],       bq1, a20, 0,0,0); \
    a21 = __builtin_amdgcn_mfma_f32_16x16x32_bf16(*(const bf16x8*)&WC_[g2_off + 2176+32],  bq1, a21, 0,0,0); \
    a20 = __builtin_amdgcn_mfma_f32_16x16x32_bf16(*(const bf16x8*)&WC_[g2_off + 64],       bq2, a20, 0,0,0); \
    a21 = __builtin_amdgcn_mfma_f32_16x16x32_bf16(*(const bf16x8*)&WC_[g2_off + 2176+64],  bq2, a21, 0,0,0); \
    a20 = __builtin_amdgcn_mfma_f32_16x16x32_bf16(*(const bf16x8*)&WC_[g2_off + 96],       bq3, a20, 0,0,0); \
    a21 = __builtin_amdgcn_mfma_f32_16x16x32_bf16(*(const bf16x8*)&WC_[g2_off + 2176+96],  bq3, a21, 0,0,0); \
    _Pragma("unroll") \
    for (int r_ = 0; r_ < 4; ++r_) { \
      int ml0_ = 32 * wm + l4 * 4 + r_; \
      int m20_ = (mt_) * 64 + ml0_; \
      OT[ml0_ * 68 + otc] = a20[r_] * (F[F_EG2 + m20_] * BNS) + F[F_EB2 + m20_]; \
      OT[(ml0_ + 16) * 68 + otc] = a21[r_] * (F[F_EG2 + m20_ + 16] * BNS) + F[F_EB2 + m20_ + 16]; \
    } \
    __syncthreads(); \
    _Pragma("unroll") \
    for (int s_ = 0; s_ < 2; ++s_) { \
      int cl_ = o_cl + 8 * s_; \
      int ch_ = (mt_) * 16 + cl_; \
      size_t ob_ = ((size_t)(bC1 + ch_) * HH + r0 + o_rr) * WW + c0 + o_p * 4; \
      int rb_ = (4 * cl_ + 2 * (o_rr & 1)) * 68 + (o_rr >> 1) * 32 + o_p; \
      float ps_ = PSs[o_p]; \
      float e0_ = OT[rb_] * ps_; \
      float e1_ = OT[rb_ + 68] * ps_; \
      float e2_ = OT[rb_ + 16] * ps_; \
      float e3_ = OT[rb_ + 68 + 16] * ps_; \
      if (BF) { ushort4 o4_ = {f2b(e0_), f2b(e1_), f2b(e2_), f2b(e3_)}; \
                *(ushort4*)((unsigned short*)outv + ob_) = o4_; } \
      else    { float4 o4_ = {e0_, e1_, e2_, e3_}; \
                *(float4*)((float*)outv + ob_) = o4_; } \
    } \
    __syncthreads(); \
  } while(0)

template<int BF>
__global__ __launch_bounds__(512, 4) void k_expert(const void* xin, void* outv, char* ws) {
  if ((*(const int*)(ws + WS_FLAG) != 0) != (BF != 0)) return;
  const float* F = (const float*)(ws + WS_F);
  const unsigned short* W1b = (const unsigned short*)(ws + WS_W16);
  const unsigned short* W2b = W1b + 131072;
  const float* pscale = (const float*)(ws + WS_PSCALE);

  // LDS union: GEMM1 {UT0,UT1,WC0,WC1} -> {O1} -> {Y2T,OT,WC20,WC21}
  __shared__ __align__(16) char LB[70720];
  unsigned short* UT0  = (unsigned short*)(LB);            // 9216 B
  unsigned short* UT1  = (unsigned short*)(LB + 9216);     // 9216 B
  unsigned short* WC0  = (unsigned short*)(LB + 18432);    // 18432 B
  unsigned short* WC1  = (unsigned short*)(LB + 36864);    // 18432 B
  float*          O1   = (float*)(LB + 18432);             // 34816 B (alias WC0/WC1)
  unsigned short* Y2T  = (unsigned short*)(LB);            // 17408 B (alias UT0/UT1)
  float*          OT   = (float*)(LB + 18432);             // 17408 B (alias O1 lo)
  unsigned short* WC20 = (unsigned short*)(LB + 35840);    // 17408 B (alias O1 hi)
  unsigned short* WC21 = (unsigned short*)(LB + 53248);    // 17408 B
  float*          PSs  = (float*)(LB + 70656);             // 64 B

  const int t = threadIdx.x;
  const int lane = t & 63;
  const int w = t >> 6;
  const int wm = w >> 2, wn = w & 3;
  const int l15 = lane & 15, l4 = lane >> 4;
  const int bid = blockIdx.x;
  const int xq = bid % 3;
  const int py = (bid / 3) % GH;
  const int b  = bid / (3 * GH);
  const int r0 = py * 4, c0 = xq * 64;
  const int bC1 = b * C1;
  const float BNS = 1.f / sqrtf(1.f + 1e-5f);

  if (t < 16) PSs[t] = pscale[b * NP + py * GW + xq * 16 + t];

  // staging coords (GEMM1)
  const int rr = (t >> 4) & 3, v4 = t & 15;
  const int n_lo72 = (32 * (rr >> 1) + v4) * 72;
  const int n_hi72 = n_lo72 + 16 * 72;
  const int kb0 = 4 * w + 2 * (rr & 1);
  const int kb1 = kb0 + 32;
  const size_t xoff0 = ((size_t)bC1 + w) * HW + (size_t)(r0 + rr) * WW + c0 + v4 * 4;
  const size_t xoff1 = xoff0 + (size_t)8 * HW;
  const int m_0 = t >> 3, k8_0 = t & 7;
  const int wi0 = m_0 * 1024 + k8_0 * 8;
  const int wi1 = (m_0 + 64) * 1024 + k8_0 * 8;
  const int wcw0 = m_0 * 72 + k8_0 * 8;
  const int wcw1 = (m_0 + 64) * 72 + k8_0 * 8;
  // mfma coords
  const int ut_off = (16 * wn + l15) * 72 + l4 * 8;
  const int wc_off = (64 * wm + l15) * 72 + l4 * 8;
  const int otc = 16 * wn + l15;
  // GEMM2 coords
  const int w2a = (t >> 3) * 136 + (t & 7) * 8;
  const int w2b = w2a + 64;
  const int w2s = (t >> 3) * 128 + (t & 7) * 8;
  const int g2_off = (32 * wm + l15) * 136 + l4 * 8;
  // store coords
  const int o_p = t & 15, o_rr = (t >> 4) & 3, o_cl = t >> 6;

  const float* xf = (const float*)xin;
  const unsigned short* xh = (const unsigned short*)xin;

  // named staging registers (NO runtime-indexed arrays -> no scratch)
  float4 Af0, Af1, Bf0, Bf1;
  ushort4 Ah0, Ah1, Bh0, Bh1;
  uint4 Aw0, Aw1, Bw0, Bw1;
  uint4 A2a, A2b, B2a, B2b;

  f32x4 acc10 = (f32x4){0.f,0.f,0.f,0.f};
  f32x4 acc11 = (f32x4){0.f,0.f,0.f,0.f};
  f32x4 acc12 = (f32x4){0.f,0.f,0.f,0.f};
  f32x4 acc13 = (f32x4){0.f,0.f,0.f,0.f};

  // ---- GEMM1: 16 K-chunks, LDS double-buffered, 1 barrier/chunk ----
  XLOAD(A, 0);
  XLOAD(B, 1);
  for (int cc2 = 0; cc2 < 8; ++cc2) {
    int cc = cc2 * 2;
    XWRITE(A, UT0, WC0);
    if (cc2 < 7) XLOAD(A, cc + 2);
    __syncthreads();
    G1_MFMA(UT0, WC0);
    XWRITE(B, UT1, WC1);
    if (cc2 < 7) XLOAD(B, cc + 3);
    __syncthreads();
    G1_MFMA(UT1, WC1);
  }

  // prefetch GEMM2 weight tiles 0,1 early (L2-resident)
  A2a = *(const uint4*)(W2b + w2s);
  A2b = *(const uint4*)(W2b + w2s + 64);
  B2a = *(const uint4*)(W2b + 8192 + w2s);
  B2b = *(const uint4*)(W2b + 8192 + w2s + 64);

  __syncthreads();               // all GEMM1 LDS reads done (O1 aliases WC)
  G1EPI(acc10, 0);
  G1EPI(acc11, 1);
  G1EPI(acc12, 2);
  G1EPI(acc13, 3);
  __syncthreads();

  // ---- depthwise 3x3 on 2x2 + BN + SiLU -> Y2T[n][h] bf16 ----
  {
    const int p = t & 15, hh = t >> 4;   // hh 0..31
#pragma unroll
    for (int s = 0; s < 4; ++s) {
      int h = hh + 32 * s;
      float i0 = O1[h * 68 + p];
      float i1 = O1[h * 68 + 16 + p];
      float i2 = O1[h * 68 + 32 + p];
      float i3 = O1[h * 68 + 48 + p];
      const float* kw = F + F_DWW + h * 9;
      float sd = F[F_DWG + h] * BNS, bd = F[F_DWB + h];
      float o00 = kw[4] * i0 + kw[5] * i1 + kw[7] * i2 + kw[8] * i3;
      float o01 = kw[3] * i0 + kw[4] * i1 + kw[6] * i2 + kw[7] * i3;
      float o10 = kw[1] * i0 + kw[2] * i1 + kw[4] * i2 + kw[5] * i3;
      float o11 = kw[0] * i0 + kw[1] * i1 + kw[3] * i2 + kw[4] * i3;
      Y2T[(0 * 16 + p) * 136 + h] = f2b(siluf(o00 * sd + bd));
      Y2T[(1 * 16 + p) * 136 + h] = f2b(siluf(o01 * sd + bd));
      Y2T[(2 * 16 + p) * 136 + h] = f2b(siluf(o10 * sd + bd));
      Y2T[(3 * 16 + p) * 136 + h] = f2b(siluf(o11 * sd + bd));
    }
  }
  __syncthreads();

  // ---- GEMM2: 16 M-tiles of 64, LDS double-buffered weights ----
  const int ybase = (16 * wn + l15) * 136 + l4 * 8;
  bf16x8 bq0 = *(const bf16x8*)&Y2T[ybase];
  bf16x8 bq1 = *(const bf16x8*)&Y2T[ybase + 32];
  bf16x8 bq2 = *(const bf16x8*)&Y2T[ybase + 64];
  bf16x8 bq3 = *(const bf16x8*)&Y2T[ybase + 96];

  for (int mtt = 0; mtt < 16; mtt += 2) {
    G2_STEP(A2, WC20, mtt);
    G2_STEP(B2, WC21, mtt + 1);
  }
}

extern "C" void kernel_launch(void* const* d_in, const int* in_sizes, int n_in,
                              void* d_out, int out_size, void* d_ws, size_t ws_size,
                              hipStream_t stream) {
  char* ws = (char*)d_ws;
  const void* x = d_in[0];
  k_detect<<<1, 256, 0, stream>>>((const unsigned short*)x, ws);
  k_prep<<<1104, 256, 0, stream>>>(d_in[1], d_in[2], d_in[3], d_in[4], d_in[5], d_in[6],
                                   d_in[7], d_in[8], d_in[9], d_in[10], d_in[11], d_in[12],
                                   d_in[13], d_in[14], ws);
  k_pool<1><<<18432, 256, 0, stream>>>(x, ws);
  k_pool<0><<<18432, 256, 0, stream>>>(x, ws);
  k_mlp<<<288, 256, 0, stream>>>(ws);
  k_route<<<72, 256, 0, stream>>>(ws);
  k_expert<1><<<1152, 512, 0, stream>>>(x, d_out, ws);
  k_expert<0><<<1152, 512, 0, stream>>>(x, d_out, ws);
}

// Round 4
// 329.316 us; speedup vs baseline: 2.2609x; 2.2609x over previous
//
#include <hip/hip_runtime.h>
#include <hip/hip_bf16.h>

typedef __attribute__((ext_vector_type(8))) short bf16x8;
typedef __attribute__((ext_vector_type(4))) float f32x4;

#define NB 8
#define C1 256
#define HH 192
#define WW 192
#define GH 48
#define GW 48
#define NP 2304
#define KSEL 576
#define RH 64
#define HID 128
#define C4 1024
#define HW (HH*WW)

// ---- workspace layout (byte offsets) ----
#define WS_FLAG 0
#define WS_F 64
#define WS_W16 81280ull
#define WS_POOLED 605696ull
#define WS_PSCALE WS_POOLED   /* pooled dead after k_mlp; reuse for pscale */
#define WS_SCORES 19480064ull

// ---- float-index offsets inside F section ----
#define F_RW1 0
#define F_RG1 16384
#define F_RB1 16448
#define F_RW2 16512
#define F_RBIAS2 16576
#define F_EG1 16580
#define F_EB1 16708
#define F_DWW 16836
#define F_DWG 17988
#define F_DWB 18116
#define F_EG2 18244
#define F_EB2 19268

__device__ __forceinline__ float b2f(unsigned short h) {
  return __uint_as_float(((unsigned)h) << 16);
}
__device__ __forceinline__ unsigned short f2b(float f) {
  unsigned u = __float_as_uint(f);
  u += 0x7FFF + ((u >> 16) & 1u);
  return (unsigned short)(u >> 16);
}
__device__ __forceinline__ float siluf(float v) { return v / (1.f + expf(-v)); }

// ---- dtype detector ----
__global__ void k_detect(const unsigned short* xb, char* ws) {
  __shared__ int cnt[256];
  int t = threadIdx.x;
  int c = 0;
  for (int s = 0; s < 32; ++s) {
    unsigned short u = xb[(t * 32 + s) * 2];
    int e = (u >> 7) & 0xFF;
    c += (u == 0 || (e >= 90 && e <= 145)) ? 1 : 0;
  }
  cnt[t] = c;
  __syncthreads();
  for (int s = 128; s > 0; s >>= 1) {
    if (t < s) cnt[t] += cnt[t + s];
    __syncthreads();
  }
  if (t == 0) *(int*)(ws + WS_FLAG) = (cnt[0] >= 4915) ? 1 : 0;
}

// ---- weight prep: fp32 params into F, expert 1x1 weights into bf16 ----
__global__ void k_prep(const void* rw1, const void* rg1, const void* rb1, const void* rw2,
                       const void* rbias2, const void* ew1, const void* eg1, const void* eb1,
                       const void* dww, const void* dwg, const void* dwb, const void* ew2,
                       const void* eg2, const void* eb2, char* ws) {
  int bf = *(const int*)(ws + WS_FLAG);
  float* F = (float*)(ws + WS_F);
  unsigned short* W16 = (unsigned short*)(ws + WS_W16);
  int i = blockIdx.x * 256 + threadIdx.x;
  if (i >= 282433) return;
  if (i < 20289) {  // fp32 section
    const void* src; int si; int dof;
    if      (i < 16384) { src = rw1;    si = i;          dof = F_RW1 + si; }
    else if (i < 16448) { src = rg1;    si = i - 16384;  dof = F_RG1 + si; }
    else if (i < 16512) { src = rb1;    si = i - 16448;  dof = F_RB1 + si; }
    else if (i < 16576) { src = rw2;    si = i - 16512;  dof = F_RW2 + si; }
    else if (i < 16577) { src = rbias2; si = i - 16576;  dof = F_RBIAS2 + si; }
    else if (i < 16705) { src = eg1;    si = i - 16577;  dof = F_EG1 + si; }
    else if (i < 16833) { src = eb1;    si = i - 16705;  dof = F_EB1 + si; }
    else if (i < 17985) { src = dww;    si = i - 16833;  dof = F_DWW + si; }
    else if (i < 18113) { src = dwg;    si = i - 17985;  dof = F_DWG + si; }
    else if (i < 18241) { src = dwb;    si = i - 18113;  dof = F_DWB + si; }
    else if (i < 19265) { src = eg2;    si = i - 18241;  dof = F_EG2 + si; }
    else                { src = eb2;    si = i - 19265;  dof = F_EB2 + si; }
    F[dof] = bf ? b2f(((const unsigned short*)src)[si]) : ((const float*)src)[si];
  } else {          // bf16 weight section: W1b then W2b
    int j = i - 20289;
    const void* src; int si; int dof;
    if (j < 131072) { src = ew1; si = j;          dof = j; }
    else            { src = ew2; si = j - 131072; dof = j; }
    W16[dof] = bf ? ((const unsigned short*)src)[si]
                  : f2b(((const float*)src)[si]);
  }
}

// ---- 4x4 avg pool (order-preserving -> identical selection) ----
template<int BF>
__global__ void k_pool(const void* xin, char* ws) {
  if ((*(const int*)(ws + WS_FLAG) != 0) != (BF != 0)) return;
  float* pooled = (float*)(ws + WS_POOLED);
  int tid = blockIdx.x * 256 + threadIdx.x;
  int px = tid % GW;
  int t2 = tid / GW;
  int py = t2 % GH;
  int bc = t2 / GH;
  size_t base = (size_t)bc * HW + (size_t)(py * 4) * WW + px * 4;
  float s = 0.f;
#pragma unroll
  for (int r = 0; r < 4; ++r) {
    if (BF) {
      const ushort4 v = *(const ushort4*)((const unsigned short*)xin + base + r * WW);
      s += b2f(v.x) + b2f(v.y) + b2f(v.z) + b2f(v.w);
    } else {
      const float4 v = *(const float4*)((const float*)xin + base + r * WW);
      s += v.x + v.y + v.z + v.w;
    }
  }
  pooled[tid] = s * 0.0625f;
}

// ---- router MLP v3: LDS-staged pooled tile + wave-uniform weight s_loads ----
// block: 512 thr = 8 waves; 64 positions/block; wave q handles h = q*8..q*8+7
__global__ __launch_bounds__(512, 2) void k_mlp(char* ws) {
  const float* F = (const float*)(ws + WS_F);
  const float* pooled = (const float*)(ws + WS_POOLED);
  float* scores = (float*)(ws + WS_SCORES);
  __shared__ float LP[256][68];   // [c][pos], padded
  __shared__ float LR[8 * 64];    // per-wave partial logits
  const int t = threadIdx.x;
  const int b = blockIdx.x / 36;
  const int pos0 = (blockIdx.x % 36) * 64;

  // stage pooled[c][pos0..pos0+63]: 16 lanes x float4 = one 256B row per 16 thr
  {
    const int pc = t & 15, c0 = t >> 4;   // 32 rows per pass
    const float* src = pooled + (size_t)(b * C1) * NP + pos0 + pc * 4;
#pragma unroll
    for (int s = 0; s < 8; ++s) {
      int c = c0 + 32 * s;
      float4 v = *(const float4*)(src + (size_t)c * NP);
      *(float4*)&LP[c][pc * 4] = v;
    }
  }
  __syncthreads();

  const int lane = t & 63;
  const int q = __builtin_amdgcn_readfirstlane(t >> 6);   // wave-uniform -> s_loads
  const float* wq = F + F_RW1 + q * 8 * C1;
  float acc[8];
#pragma unroll
  for (int j = 0; j < 8; ++j) acc[j] = 0.f;
  for (int c = 0; c < 256; c += 4) {
    float p0 = LP[c + 0][lane];
    float p1 = LP[c + 1][lane];
    float p2 = LP[c + 2][lane];
    float p3 = LP[c + 3][lane];
#pragma unroll
    for (int j = 0; j < 8; ++j) {
      // same per-h ascending-c order as prior rounds (bitwise-identical sums)
      acc[j] += wq[j * C1 + c + 0] * p0;
      acc[j] += wq[j * C1 + c + 1] * p1;
      acc[j] += wq[j * C1 + c + 2] * p2;
      acc[j] += wq[j * C1 + c + 3] * p3;
    }
  }
  const float BNS = 1.f / sqrtf(1.f + 1e-5f);
  float lp = 0.f;
#pragma unroll
  for (int j = 0; j < 8; ++j) {
    int h = q * 8 + j;
    float v = acc[j] * (F[F_RG1 + h] * BNS) + F[F_RB1 + h];
    lp += F[F_RW2 + h] * siluf(v);
  }
  LR[q * 64 + lane] = lp;
  __syncthreads();
  if (t < 64) {
    float s = F[F_RBIAS2];
#pragma unroll
    for (int j = 0; j < 8; ++j) s += LR[j * 64 + t];
    scores[b * NP + pos0 + t] = 1.f / (1.f + expf(-s));
  }
}

// ---- per-patch scale: score if in top-k else 0 ----
__global__ void k_route(char* ws) {
  const float* scores = (const float*)(ws + WS_SCORES);
  float* pscale = (float*)(ws + WS_PSCALE);
  int b = blockIdx.x / 9, r = blockIdx.x % 9;
  __shared__ float s[NP];
  for (int i = threadIdx.x; i < NP; i += 256) s[i] = scores[b * NP + i];
  __syncthreads();
  int i = r * 256 + threadIdx.x;
  float si = s[i];
  int rank = 0;
  for (int j = 0; j < NP; ++j) {
    float sj = s[j];
    rank += (sj > si || (sj == si && j < i)) ? 1 : 0;
  }
  pscale[b * NP + i] = (rank < KSEL) ? si : 0.f;
}

// ======================= dense expert =======================
// n-labeling: n = pix*16 + patch  (pix = pr*2+pc within 2x2, patch = 0..15)

#define XLOAD(P_, cc_) do { \
    size_t o_ = (size_t)(cc_) * 16 * HW; \
    if (BF) { P_##h0 = *(const ushort4*)(xh + xoff0 + o_); \
              P_##h1 = *(const ushort4*)(xh + xoff1 + o_); } \
    else    { P_##f0 = *(const float4*)(xf + xoff0 + o_); \
              P_##f1 = *(const float4*)(xf + xoff1 + o_); } \
    const unsigned short* wp_ = W1b + (cc_) * 64; \
    P_##w0 = *(const uint4*)(wp_ + wi0); \
    P_##w1 = *(const uint4*)(wp_ + wi1); \
  } while(0)

#define XWRITE(P_, UT_, WC_) do { \
    unsigned lo0_, hi0_, lo1_, hi1_; \
    if (BF) { lo0_ = P_##h0.x | ((unsigned)P_##h0.y << 16); hi0_ = P_##h0.z | ((unsigned)P_##h0.w << 16); \
              lo1_ = P_##h1.x | ((unsigned)P_##h1.y << 16); hi1_ = P_##h1.z | ((unsigned)P_##h1.w << 16); } \
    else    { lo0_ = f2b(P_##f0.x) | ((unsigned)f2b(P_##f0.y) << 16); hi0_ = f2b(P_##f0.z) | ((unsigned)f2b(P_##f0.w) << 16); \
              lo1_ = f2b(P_##f1.x) | ((unsigned)f2b(P_##f1.y) << 16); hi1_ = f2b(P_##f1.z) | ((unsigned)f2b(P_##f1.w) << 16); } \
    *(unsigned*)&UT_[n_lo72 + kb0] = lo0_; \
    *(unsigned*)&UT_[n_hi72 + kb0] = hi0_; \
    *(unsigned*)&UT_[n_lo72 + kb1] = lo1_; \
    *(unsigned*)&UT_[n_hi72 + kb1] = hi1_; \
    *(uint4*)&WC_[wcw0] = P_##w0; \
    *(uint4*)&WC_[wcw1] = P_##w1; \
  } while(0)

#define MFMA1(WCO_, B_, ACC_) ACC_ = __builtin_amdgcn_mfma_f32_16x16x32_bf16(*(const bf16x8*)&WC_[wc_off + (WCO_)], B_, ACC_, 0, 0, 0)

#define G1_MFMA(UT_, WCp_) do { \
    const unsigned short* WC_ = WCp_; \
    bf16x8 b0_ = *(const bf16x8*)&UT_[ut_off]; \
    bf16x8 b1_ = *(const bf16x8*)&UT_[ut_off + 32]; \
    MFMA1(0, b0_, acc10);    MFMA1(1152, b0_, acc11); \
    MFMA1(2304, b0_, acc12); MFMA1(3456, b0_, acc13); \
    MFMA1(32, b1_, acc10);   MFMA1(1152+32, b1_, acc11); \
    MFMA1(2304+32, b1_, acc12); MFMA1(3456+32, b1_, acc13); \
  } while(0)

#define G1EPI(ACC_, mi_) do { \
    _Pragma("unroll") \
    for (int r_ = 0; r_ < 4; ++r_) { \
      int h_ = 64 * wm + 16 * (mi_) + l4 * 4 + r_; \
      O1[h_ * 68 + otc] = siluf(ACC_[r_] * (F[F_EG1 + h_] * BNS) + F[F_EB1 + h_]); \
    } \
  } while(0)

#define G2_STEP(P_, WCp_, mt_) do { \
    const unsigned short* WC_ = WCp_; \
    *(uint4*)&((unsigned short*)WCp_)[w2a] = P_##a; \
    *(uint4*)&((unsigned short*)WCp_)[w2b] = P_##b; \
    if ((mt_) < 14) { \
      const unsigned short* wp_ = W2b + (size_t)((mt_) + 2) * 8192; \
      P_##a = *(const uint4*)(wp_ + w2s); \
      P_##b = *(const uint4*)(wp_ + w2s + 64); \
    } \
    __syncthreads(); \
    f32x4 a20 = (f32x4){0.f, 0.f, 0.f, 0.f}; \
    f32x4 a21 = (f32x4){0.f, 0.f, 0.f, 0.f}; \
    a20 = __builtin_amdgcn_mfma_f32_16x16x32_bf16(*(const bf16x8*)&WC_[g2_off + 0],        bq0, a20, 0,0,0); \
    a21 = __builtin_amdgcn_mfma_f32_16x16x32_bf16(*(const bf16x8*)&WC_[g2_off + 2176],     bq0, a21, 0,0,0); \
    a20 = __builtin_amdgcn_mfma_f32_16x16x32_bf16(*(const bf16x8*)&WC_[g2_off + 32],       bq1, a20, 0,0,0); \
    a21 = __builtin_amdgcn_mfma_f32_16x16x32_bf16(*(const bf16x8*)&WC_[g2_off + 2176+32],  bq1, a21, 0,0,0); \
    a20 = __builtin_amdgcn_mfma_f32_16x16x32_bf16(*(const bf16x8*)&WC_[g2_off + 64],       bq2, a20, 0,0,0); \
    a21 = __builtin_amdgcn_mfma_f32_16x16x32_bf16(*(const bf16x8*)&WC_[g2_off + 2176+64],  bq2, a21, 0,0,0); \
    a20 = __builtin_amdgcn_mfma_f32_16x16x32_bf16(*(const bf16x8*)&WC_[g2_off + 96],       bq3, a20, 0,0,0); \
    a21 = __builtin_amdgcn_mfma_f32_16x16x32_bf16(*(const bf16x8*)&WC_[g2_off + 2176+96],  bq3, a21, 0,0,0); \
    _Pragma("unroll") \
    for (int r_ = 0; r_ < 4; ++r_) { \
      int ml0_ = 32 * wm + l4 * 4 + r_; \
      int m20_ = (mt_) * 64 + ml0_; \
      OT[ml0_ * 68 + otc] = a20[r_] * (F[F_EG2 + m20_] * BNS) + F[F_EB2 + m20_]; \
      OT[(ml0_ + 16) * 68 + otc] = a21[r_] * (F[F_EG2 + m20_ + 16] * BNS) + F[F_EB2 + m20_ + 16]; \
    } \
    __syncthreads(); \
    _Pragma("unroll") \
    for (int s_ = 0; s_ < 2; ++s_) { \
      int cl_ = o_cl + 8 * s_; \
      int ch_ = (mt_) * 16 + cl_; \
      size_t ob_ = ((size_t)(bC1 + ch_) * HH + r0 + o_rr) * WW + c0 + o_p * 4; \
      int rb_ = (4 * cl_ + 2 * (o_rr & 1)) * 68 + (o_rr >> 1) * 32 + o_p; \
      float ps_ = PSs[o_p]; \
      float e0_ = OT[rb_] * ps_; \
      float e1_ = OT[rb_ + 68] * ps_; \
      float e2_ = OT[rb_ + 16] * ps_; \
      float e3_ = OT[rb_ + 68 + 16] * ps_; \
      if (BF) { ushort4 o4_ = {f2b(e0_), f2b(e1_), f2b(e2_), f2b(e3_)}; \
                *(ushort4*)((unsigned short*)outv + ob_) = o4_; } \
      else    { float4 o4_ = {e0_, e1_, e2_, e3_}; \
                *(float4*)((float*)outv + ob_) = o4_; } \
    } \
    __syncthreads(); \
  } while(0)

template<int BF>
__global__ __launch_bounds__(512, 4) void k_expert(const void* xin, void* outv, char* ws) {
  if ((*(const int*)(ws + WS_FLAG) != 0) != (BF != 0)) return;
  const float* F = (const float*)(ws + WS_F);
  const unsigned short* W1b = (const unsigned short*)(ws + WS_W16);
  const unsigned short* W2b = W1b + 131072;
  const float* pscale = (const float*)(ws + WS_PSCALE);

  // LDS union: GEMM1 {UT0,UT1,WC0,WC1} -> {O1} -> {Y2T,OT,WC20,WC21}
  __shared__ __align__(16) char LB[70720];
  unsigned short* UT0  = (unsigned short*)(LB);            // 9216 B
  unsigned short* UT1  = (unsigned short*)(LB + 9216);     // 9216 B
  unsigned short* WC0  = (unsigned short*)(LB + 18432);    // 18432 B
  unsigned short* WC1  = (unsigned short*)(LB + 36864);    // 18432 B
  float*          O1   = (float*)(LB + 18432);             // 34816 B (alias WC0/WC1)
  unsigned short* Y2T  = (unsigned short*)(LB);            // 17408 B (alias UT0/UT1)
  float*          OT   = (float*)(LB + 18432);             // 17408 B (alias O1 lo)
  unsigned short* WC20 = (unsigned short*)(LB + 35840);    // 17408 B (alias O1 hi)
  unsigned short* WC21 = (unsigned short*)(LB + 53248);    // 17408 B
  float*          PSs  = (float*)(LB + 70656);             // 64 B

  const int t = threadIdx.x;
  const int lane = t & 63;
  const int w = t >> 6;
  const int wm = w >> 2, wn = w & 3;
  const int l15 = lane & 15, l4 = lane >> 4;
  const int bid = blockIdx.x;
  const int xq = bid % 3;
  const int py = (bid / 3) % GH;
  const int b  = bid / (3 * GH);
  const int r0 = py * 4, c0 = xq * 64;
  const int bC1 = b * C1;
  const float BNS = 1.f / sqrtf(1.f + 1e-5f);

  if (t < 16) PSs[t] = pscale[b * NP + py * GW + xq * 16 + t];

  // staging coords (GEMM1)
  const int rr = (t >> 4) & 3, v4 = t & 15;
  const int n_lo72 = (32 * (rr >> 1) + v4) * 72;
  const int n_hi72 = n_lo72 + 16 * 72;
  const int kb0 = 4 * w + 2 * (rr & 1);
  const int kb1 = kb0 + 32;
  const size_t xoff0 = ((size_t)bC1 + w) * HW + (size_t)(r0 + rr) * WW + c0 + v4 * 4;
  const size_t xoff1 = xoff0 + (size_t)8 * HW;
  const int m_0 = t >> 3, k8_0 = t & 7;
  const int wi0 = m_0 * 1024 + k8_0 * 8;
  const int wi1 = (m_0 + 64) * 1024 + k8_0 * 8;
  const int wcw0 = m_0 * 72 + k8_0 * 8;
  const int wcw1 = (m_0 + 64) * 72 + k8_0 * 8;
  // mfma coords
  const int ut_off = (16 * wn + l15) * 72 + l4 * 8;
  const int wc_off = (64 * wm + l15) * 72 + l4 * 8;
  const int otc = 16 * wn + l15;
  // GEMM2 coords
  const int w2a = (t >> 3) * 136 + (t & 7) * 8;
  const int w2b = w2a + 64;
  const int w2s = (t >> 3) * 128 + (t & 7) * 8;
  const int g2_off = (32 * wm + l15) * 136 + l4 * 8;
  // store coords
  const int o_p = t & 15, o_rr = (t >> 4) & 3, o_cl = t >> 6;

  const float* xf = (const float*)xin;
  const unsigned short* xh = (const unsigned short*)xin;

  // named staging registers (NO runtime-indexed arrays -> no scratch)
  float4 Af0, Af1, Bf0, Bf1;
  ushort4 Ah0, Ah1, Bh0, Bh1;
  uint4 Aw0, Aw1, Bw0, Bw1;
  uint4 A2a, A2b, B2a, B2b;

  f32x4 acc10 = (f32x4){0.f,0.f,0.f,0.f};
  f32x4 acc11 = (f32x4){0.f,0.f,0.f,0.f};
  f32x4 acc12 = (f32x4){0.f,0.f,0.f,0.f};
  f32x4 acc13 = (f32x4){0.f,0.f,0.f,0.f};

  // ---- GEMM1: 16 K-chunks, LDS double-buffered, 1 barrier/chunk ----
  XLOAD(A, 0);
  XLOAD(B, 1);
  for (int cc2 = 0; cc2 < 8; ++cc2) {
    int cc = cc2 * 2;
    XWRITE(A, UT0, WC0);
    if (cc2 < 7) XLOAD(A, cc + 2);
    __syncthreads();
    G1_MFMA(UT0, WC0);
    XWRITE(B, UT1, WC1);
    if (cc2 < 7) XLOAD(B, cc + 3);
    __syncthreads();
    G1_MFMA(UT1, WC1);
  }

  // prefetch GEMM2 weight tiles 0,1 early (L2-resident)
  A2a = *(const uint4*)(W2b + w2s);
  A2b = *(const uint4*)(W2b + w2s + 64);
  B2a = *(const uint4*)(W2b + 8192 + w2s);
  B2b = *(const uint4*)(W2b + 8192 + w2s + 64);

  __syncthreads();               // all GEMM1 LDS reads done (O1 aliases WC)
  G1EPI(acc10, 0);
  G1EPI(acc11, 1);
  G1EPI(acc12, 2);
  G1EPI(acc13, 3);
  __syncthreads();

  // ---- depthwise 3x3 on 2x2 + BN + SiLU -> Y2T[n][h] bf16 ----
  {
    const int p = t & 15, hh = t >> 4;   // hh 0..31
#pragma unroll
    for (int s = 0; s < 4; ++s) {
      int h = hh + 32 * s;
      float i0 = O1[h * 68 + p];
      float i1 = O1[h * 68 + 16 + p];
      float i2 = O1[h * 68 + 32 + p];
      float i3 = O1[h * 68 + 48 + p];
      const float* kw = F + F_DWW + h * 9;
      float sd = F[F_DWG + h] * BNS, bd = F[F_DWB + h];
      float o00 = kw[4] * i0 + kw[5] * i1 + kw[7] * i2 + kw[8] * i3;
      float o01 = kw[3] * i0 + kw[4] * i1 + kw[6] * i2 + kw[7] * i3;
      float o10 = kw[1] * i0 + kw[2] * i1 + kw[4] * i2 + kw[5] * i3;
      float o11 = kw[0] * i0 + kw[1] * i1 + kw[3] * i2 + kw[4] * i3;
      Y2T[(0 * 16 + p) * 136 + h] = f2b(siluf(o00 * sd + bd));
      Y2T[(1 * 16 + p) * 136 + h] = f2b(siluf(o01 * sd + bd));
      Y2T[(2 * 16 + p) * 136 + h] = f2b(siluf(o10 * sd + bd));
      Y2T[(3 * 16 + p) * 136 + h] = f2b(siluf(o11 * sd + bd));
    }
  }
  __syncthreads();

  // ---- GEMM2: 16 M-tiles of 64, LDS double-buffered weights ----
  const int ybase = (16 * wn + l15) * 136 + l4 * 8;
  bf16x8 bq0 = *(const bf16x8*)&Y2T[ybase];
  bf16x8 bq1 = *(const bf16x8*)&Y2T[ybase + 32];
  bf16x8 bq2 = *(const bf16x8*)&Y2T[ybase + 64];
  bf16x8 bq3 = *(const bf16x8*)&Y2T[ybase + 96];

  for (int mtt = 0; mtt < 16; mtt += 2) {
    G2_STEP(A2, WC20, mtt);
    G2_STEP(B2, WC21, mtt + 1);
  }
}

extern "C" void kernel_launch(void* const* d_in, const int* in_sizes, int n_in,
                              void* d_out, int out_size, void* d_ws, size_t ws_size,
                              hipStream_t stream) {
  char* ws = (char*)d_ws;
  const void* x = d_in[0];
  k_detect<<<1, 256, 0, stream>>>((const unsigned short*)x, ws);
  k_prep<<<1104, 256, 0, stream>>>(d_in[1], d_in[2], d_in[3], d_in[4], d_in[5], d_in[6],
                                   d_in[7], d_in[8], d_in[9], d_in[10], d_in[11], d_in[12],
                                   d_in[13], d_in[14], ws);
  k_pool<1><<<18432, 256, 0, stream>>>(x, ws);
  k_pool<0><<<18432, 256, 0, stream>>>(x, ws);
  k_mlp<<<288, 512, 0, stream>>>(ws);
  k_route<<<72, 256, 0, stream>>>(ws);
  k_expert<1><<<1152, 512, 0, stream>>>(x, d_out, ws);
  k_expert<0><<<1152, 512, 0, stream>>>(x, d_out, ws);
}

// Round 5
// 319.916 us; speedup vs baseline: 2.3273x; 1.0294x over previous
//
#include <hip/hip_runtime.h>
#include <hip/hip_bf16.h>

typedef __attribute__((ext_vector_type(8))) short bf16x8;
typedef __attribute__((ext_vector_type(4))) float f32x4;

#define NB 8
#define C1 256
#define HH 192
#define WW 192
#define GH 48
#define GW 48
#define NP 2304
#define KSEL 576
#define RH 64
#define HID 128
#define C4 1024
#define HW (HH*WW)

// ---- workspace layout (byte offsets) ----
#define WS_FLAG 0
#define WS_F 64
#define WS_W16 81280ull
#define WS_POOLED 605696ull
#define WS_PSCALE WS_POOLED   /* pooled dead after k_mlp; reuse for pscale */
#define WS_SCORES 19480064ull

// ---- float-index offsets inside F section ----
#define F_RW1 0
#define F_RG1 16384
#define F_RB1 16448
#define F_RW2 16512
#define F_RBIAS2 16576
#define F_EG1 16580
#define F_EB1 16708
#define F_DWW 16836
#define F_DWG 17988
#define F_DWB 18116
#define F_EG2 18244
#define F_EB2 19268

__device__ __forceinline__ float b2f(unsigned short h) {
  return __uint_as_float(((unsigned)h) << 16);
}
__device__ __forceinline__ unsigned short f2b(float f) {
  unsigned u = __float_as_uint(f);
  u += 0x7FFF + ((u >> 16) & 1u);
  return (unsigned short)(u >> 16);
}
__device__ __forceinline__ float siluf(float v) { return v / (1.f + expf(-v)); }

// ---- dtype detector: 2048 spread samples of even-u16 exponent sanity ----
__global__ void k_detect(const unsigned short* xb, char* ws) {
  __shared__ int cnt[256];
  int t = threadIdx.x;
  int c = 0;
#pragma unroll
  for (int s = 0; s < 8; ++s) {
    unsigned short u = xb[(size_t)(t * 8 + s) * 1024];   // even u16 indices, 4MB span
    int e = (u >> 7) & 0xFF;
    c += (u == 0 || (e >= 90 && e <= 145)) ? 1 : 0;
  }
  cnt[t] = c;
  __syncthreads();
  for (int s = 128; s > 0; s >>= 1) {
    if (t < s) cnt[t] += cnt[t + s];
    __syncthreads();
  }
  if (t == 0) *(int*)(ws + WS_FLAG) = (cnt[0] >= 1229) ? 1 : 0;  // 60% of 2048
}

// ---- weight prep: fp32 params into F, expert 1x1 weights into bf16 ----
__global__ void k_prep(const void* rw1, const void* rg1, const void* rb1, const void* rw2,
                       const void* rbias2, const void* ew1, const void* eg1, const void* eb1,
                       const void* dww, const void* dwg, const void* dwb, const void* ew2,
                       const void* eg2, const void* eb2, char* ws) {
  int bf = *(const int*)(ws + WS_FLAG);
  float* F = (float*)(ws + WS_F);
  unsigned short* W16 = (unsigned short*)(ws + WS_W16);
  int i = blockIdx.x * 256 + threadIdx.x;
  if (i >= 282433) return;
  if (i < 20289) {  // fp32 section
    const void* src; int si; int dof;
    if      (i < 16384) { src = rw1;    si = i;          dof = F_RW1 + si; }
    else if (i < 16448) { src = rg1;    si = i - 16384;  dof = F_RG1 + si; }
    else if (i < 16512) { src = rb1;    si = i - 16448;  dof = F_RB1 + si; }
    else if (i < 16576) { src = rw2;    si = i - 16512;  dof = F_RW2 + si; }
    else if (i < 16577) { src = rbias2; si = i - 16576;  dof = F_RBIAS2 + si; }
    else if (i < 16705) { src = eg1;    si = i - 16577;  dof = F_EG1 + si; }
    else if (i < 16833) { src = eb1;    si = i - 16705;  dof = F_EB1 + si; }
    else if (i < 17985) { src = dww;    si = i - 16833;  dof = F_DWW + si; }
    else if (i < 18113) { src = dwg;    si = i - 17985;  dof = F_DWG + si; }
    else if (i < 18241) { src = dwb;    si = i - 18113;  dof = F_DWB + si; }
    else if (i < 19265) { src = eg2;    si = i - 18241;  dof = F_EG2 + si; }
    else                { src = eb2;    si = i - 19265;  dof = F_EB2 + si; }
    F[dof] = bf ? b2f(((const unsigned short*)src)[si]) : ((const float*)src)[si];
  } else {          // bf16 weight section: W1b then W2b
    int j = i - 20289;
    const void* src; int si; int dof;
    if (j < 131072) { src = ew1; si = j;          dof = j; }
    else            { src = ew2; si = j - 131072; dof = j; }
    W16[dof] = bf ? ((const unsigned short*)src)[si]
                  : f2b(((const float*)src)[si]);
  }
}

// ---- 4x4 avg pool (order-preserving -> identical selection) ----
__global__ void k_pool(const void* xin, char* ws) {
  const int bf = *(const int*)(ws + WS_FLAG);
  float* pooled = (float*)(ws + WS_POOLED);
  int tid = blockIdx.x * 256 + threadIdx.x;
  int px = tid % GW;
  int t2 = tid / GW;
  int py = t2 % GH;
  int bc = t2 / GH;
  size_t base = (size_t)bc * HW + (size_t)(py * 4) * WW + px * 4;
  float s = 0.f;
  if (bf) {
#pragma unroll
    for (int r = 0; r < 4; ++r) {
      const ushort4 v = *(const ushort4*)((const unsigned short*)xin + base + r * WW);
      s += b2f(v.x) + b2f(v.y) + b2f(v.z) + b2f(v.w);
    }
  } else {
#pragma unroll
    for (int r = 0; r < 4; ++r) {
      const float4 v = *(const float4*)((const float*)xin + base + r * WW);
      s += v.x + v.y + v.z + v.w;
    }
  }
  pooled[tid] = s * 0.0625f;
}

// ---- router MLP: LDS-staged pooled tile + wave-uniform weight s_loads ----
__global__ __launch_bounds__(512, 2) void k_mlp(char* ws) {
  const float* F = (const float*)(ws + WS_F);
  const float* pooled = (const float*)(ws + WS_POOLED);
  float* scores = (float*)(ws + WS_SCORES);
  __shared__ float LP[256][68];   // [c][pos], padded
  __shared__ float LR[8 * 64];    // per-wave partial logits
  const int t = threadIdx.x;
  const int b = blockIdx.x / 36;
  const int pos0 = (blockIdx.x % 36) * 64;

  {
    const int pc = t & 15, c0 = t >> 4;   // 32 rows per pass
    const float* src = pooled + (size_t)(b * C1) * NP + pos0 + pc * 4;
#pragma unroll
    for (int s = 0; s < 8; ++s) {
      int c = c0 + 32 * s;
      float4 v = *(const float4*)(src + (size_t)c * NP);
      *(float4*)&LP[c][pc * 4] = v;
    }
  }
  __syncthreads();

  const int lane = t & 63;
  const int q = __builtin_amdgcn_readfirstlane(t >> 6);   // wave-uniform -> s_loads
  const float* wq = F + F_RW1 + q * 8 * C1;
  float acc[8];
#pragma unroll
  for (int j = 0; j < 8; ++j) acc[j] = 0.f;
  for (int c = 0; c < 256; c += 4) {
    float p0 = LP[c + 0][lane];
    float p1 = LP[c + 1][lane];
    float p2 = LP[c + 2][lane];
    float p3 = LP[c + 3][lane];
#pragma unroll
    for (int j = 0; j < 8; ++j) {
      acc[j] += wq[j * C1 + c + 0] * p0;
      acc[j] += wq[j * C1 + c + 1] * p1;
      acc[j] += wq[j * C1 + c + 2] * p2;
      acc[j] += wq[j * C1 + c + 3] * p3;
    }
  }
  const float BNS = 1.f / sqrtf(1.f + 1e-5f);
  float lp = 0.f;
#pragma unroll
  for (int j = 0; j < 8; ++j) {
    int h = q * 8 + j;
    float v = acc[j] * (F[F_RG1 + h] * BNS) + F[F_RB1 + h];
    lp += F[F_RW2 + h] * siluf(v);
  }
  LR[q * 64 + lane] = lp;
  __syncthreads();
  if (t < 64) {
    float s = F[F_RBIAS2];
#pragma unroll
    for (int j = 0; j < 8; ++j) s += LR[j * 64 + t];
    scores[b * NP + pos0 + t] = 1.f / (1.f + expf(-s));
  }
}

// ---- per-patch scale: score if in top-k else 0 ----
__global__ void k_route(char* ws) {
  const float* scores = (const float*)(ws + WS_SCORES);
  float* pscale = (float*)(ws + WS_PSCALE);
  int b = blockIdx.x / 9, r = blockIdx.x % 9;
  __shared__ float s[NP];
  for (int i = threadIdx.x; i < NP; i += 256) s[i] = scores[b * NP + i];
  __syncthreads();
  int i = r * 256 + threadIdx.x;
  float si = s[i];
  int rank = 0;
  for (int j = 0; j < NP; ++j) {
    float sj = s[j];
    rank += (sj > si || (sj == si && j < i)) ? 1 : 0;
  }
  pscale[b * NP + i] = (rank < KSEL) ? si : 0.f;
}

// ======================= dense expert =======================
// n-labeling: n = pix*16 + patch  (pix = pr*2+pc within 2x2, patch = 0..15)

#define XLOAD(P_, cc_) do { \
    if (sel) { \
      size_t o_ = (size_t)(cc_) * 16 * HW; \
      if (BF) { P_##h0 = *(const ushort4*)(xh + xoff0 + o_); \
                P_##h1 = *(const ushort4*)(xh + xoff1 + o_); } \
      else    { P_##f0 = *(const float4*)(xf + xoff0 + o_); \
                P_##f1 = *(const float4*)(xf + xoff1 + o_); } \
    } \
    const unsigned short* wp_ = W1b + (cc_) * 64; \
    P_##w0 = *(const uint4*)(wp_ + wi0); \
    P_##w1 = *(const uint4*)(wp_ + wi1); \
  } while(0)

#define XWRITE(P_, UT_, WC_) do { \
    unsigned lo0_, hi0_, lo1_, hi1_; \
    if (BF) { lo0_ = P_##h0.x | ((unsigned)P_##h0.y << 16); hi0_ = P_##h0.z | ((unsigned)P_##h0.w << 16); \
              lo1_ = P_##h1.x | ((unsigned)P_##h1.y << 16); hi1_ = P_##h1.z | ((unsigned)P_##h1.w << 16); } \
    else    { asm("v_cvt_pk_bf16_f32 %0, %1, %2" : "=v"(lo0_) : "v"(P_##f0.x), "v"(P_##f0.y)); \
              asm("v_cvt_pk_bf16_f32 %0, %1, %2" : "=v"(hi0_) : "v"(P_##f0.z), "v"(P_##f0.w)); \
              asm("v_cvt_pk_bf16_f32 %0, %1, %2" : "=v"(lo1_) : "v"(P_##f1.x), "v"(P_##f1.y)); \
              asm("v_cvt_pk_bf16_f32 %0, %1, %2" : "=v"(hi1_) : "v"(P_##f1.z), "v"(P_##f1.w)); } \
    *(unsigned*)&UT_[n_lo72 + kb0] = lo0_; \
    *(unsigned*)&UT_[n_hi72 + kb0] = hi0_; \
    *(unsigned*)&UT_[n_lo72 + kb1] = lo1_; \
    *(unsigned*)&UT_[n_hi72 + kb1] = hi1_; \
    *(uint4*)&WC_[wcw0] = P_##w0; \
    *(uint4*)&WC_[wcw1] = P_##w1; \
  } while(0)

#define MFMA1(WCO_, B_, ACC_) ACC_ = __builtin_amdgcn_mfma_f32_16x16x32_bf16(*(const bf16x8*)&WC_[wc_off + (WCO_)], B_, ACC_, 0, 0, 0)

#define G1_MFMA(UT_, WCp_) do { \
    const unsigned short* WC_ = WCp_; \
    bf16x8 b0_ = *(const bf16x8*)&UT_[ut_off]; \
    bf16x8 b1_ = *(const bf16x8*)&UT_[ut_off + 32]; \
    MFMA1(0, b0_, acc10);    MFMA1(1152, b0_, acc11); \
    MFMA1(2304, b0_, acc12); MFMA1(3456, b0_, acc13); \
    MFMA1(32, b1_, acc10);   MFMA1(1152+32, b1_, acc11); \
    MFMA1(2304+32, b1_, acc12); MFMA1(3456+32, b1_, acc13); \
  } while(0)

#define G1EPI(ACC_, mi_) do { \
    _Pragma("unroll") \
    for (int r_ = 0; r_ < 4; ++r_) { \
      int h_ = 64 * wm + 16 * (mi_) + l4 * 4 + r_; \
      O1[h_ * 68 + otc] = siluf(ACC_[r_] * (F[F_EG1 + h_] * BNS) + F[F_EB1 + h_]); \
    } \
  } while(0)

#define G2_STEP(P_, WCp_, mt_) do { \
    const unsigned short* WC_ = WCp_; \
    *(uint4*)&((unsigned short*)WCp_)[w2a] = P_##a; \
    *(uint4*)&((unsigned short*)WCp_)[w2b] = P_##b; \
    if ((mt_) < 14) { \
      const unsigned short* wp_ = W2b + (size_t)((mt_) + 2) * 8192; \
      P_##a = *(const uint4*)(wp_ + w2s); \
      P_##b = *(const uint4*)(wp_ + w2s + 64); \
    } \
    __syncthreads(); \
    f32x4 a20 = (f32x4){0.f, 0.f, 0.f, 0.f}; \
    f32x4 a21 = (f32x4){0.f, 0.f, 0.f, 0.f}; \
    a20 = __builtin_amdgcn_mfma_f32_16x16x32_bf16(*(const bf16x8*)&WC_[g2_off + 0],        bq0, a20, 0,0,0); \
    a21 = __builtin_amdgcn_mfma_f32_16x16x32_bf16(*(const bf16x8*)&WC_[g2_off + 2176],     bq0, a21, 0,0,0); \
    a20 = __builtin_amdgcn_mfma_f32_16x16x32_bf16(*(const bf16x8*)&WC_[g2_off + 32],       bq1, a20, 0,0,0); \
    a21 = __builtin_amdgcn_mfma_f32_16x16x32_bf16(*(const bf16x8*)&WC_[g2_off + 2176+32],  bq1, a21, 0,0,0); \
    a20 = __builtin_amdgcn_mfma_f32_16x16x32_bf16(*(const bf16x8*)&WC_[g2_off + 64],       bq2, a20, 0,0,0); \
    a21 = __builtin_amdgcn_mfma_f32_16x16x32_bf16(*(const bf16x8*)&WC_[g2_off + 2176+64],  bq2, a21, 0,0,0); \
    a20 = __builtin_amdgcn_mfma_f32_16x16x32_bf16(*(const bf16x8*)&WC_[g2_off + 96],       bq3, a20, 0,0,0); \
    a21 = __builtin_amdgcn_mfma_f32_16x16x32_bf16(*(const bf16x8*)&WC_[g2_off + 2176+96],  bq3, a21, 0,0,0); \
    _Pragma("unroll") \
    for (int r_ = 0; r_ < 4; ++r_) { \
      int ml0_ = 32 * wm + l4 * 4 + r_; \
      int m20_ = (mt_) * 64 + ml0_; \
      OT[ml0_ * 68 + otc] = a20[r_] * (F[F_EG2 + m20_] * BNS) + F[F_EB2 + m20_]; \
      OT[(ml0_ + 16) * 68 + otc] = a21[r_] * (F[F_EG2 + m20_ + 16] * BNS) + F[F_EB2 + m20_ + 16]; \
    } \
    __syncthreads(); \
    _Pragma("unroll") \
    for (int s_ = 0; s_ < 2; ++s_) { \
      int cl_ = o_cl + 8 * s_; \
      int ch_ = (mt_) * 16 + cl_; \
      size_t ob_ = ((size_t)(bC1 + ch_) * HH + r0 + o_rr) * WW + c0 + o_p * 4; \
      int rb_ = (4 * cl_ + 2 * (o_rr & 1)) * 68 + (o_rr >> 1) * 32 + o_p; \
      float ps_ = PSs[o_p]; \
      float e0_ = OT[rb_] * ps_; \
      float e1_ = OT[rb_ + 68] * ps_; \
      float e2_ = OT[rb_ + 16] * ps_; \
      float e3_ = OT[rb_ + 68 + 16] * ps_; \
      if (BF) { ushort4 o4_ = {f2b(e0_), f2b(e1_), f2b(e2_), f2b(e3_)}; \
                *(ushort4*)((unsigned short*)outv + ob_) = o4_; } \
      else    { float4 o4_ = {e0_, e1_, e2_, e3_}; \
                *(float4*)((float*)outv + ob_) = o4_; } \
    } \
    __syncthreads(); \
  } while(0)

__global__ __launch_bounds__(512, 4) void k_expert(const void* xin, void* outv, char* ws) {
  const int BF = *(const int*)(ws + WS_FLAG);
  const float* F = (const float*)(ws + WS_F);
  const unsigned short* W1b = (const unsigned short*)(ws + WS_W16);
  const unsigned short* W2b = W1b + 131072;
  const float* pscale = (const float*)(ws + WS_PSCALE);

  // LDS union: GEMM1 {UT0,UT1,WC0,WC1} -> {O1} -> {Y2T,OT,WC20,WC21}
  __shared__ __align__(16) char LB[70720];
  unsigned short* UT0  = (unsigned short*)(LB);            // 9216 B
  unsigned short* UT1  = (unsigned short*)(LB + 9216);     // 9216 B
  unsigned short* WC0  = (unsigned short*)(LB + 18432);    // 18432 B
  unsigned short* WC1  = (unsigned short*)(LB + 36864);    // 18432 B
  float*          O1   = (float*)(LB + 18432);             // 34816 B (alias WC0/WC1)
  unsigned short* Y2T  = (unsigned short*)(LB);            // 17408 B (alias UT0/UT1)
  float*          OT   = (float*)(LB + 18432);             // 17408 B (alias O1 lo)
  unsigned short* WC20 = (unsigned short*)(LB + 35840);    // 17408 B (alias O1 hi)
  unsigned short* WC21 = (unsigned short*)(LB + 53248);    // 17408 B
  float*          PSs  = (float*)(LB + 70656);             // 64 B

  const int t = threadIdx.x;
  const int lane = t & 63;
  const int w = t >> 6;
  const int wm = w >> 2, wn = w & 3;
  const int l15 = lane & 15, l4 = lane >> 4;
  const int bid = blockIdx.x;
  const int xq = bid % 3;
  const int py = (bid / 3) % GH;
  const int b  = bid / (3 * GH);
  const int r0 = py * 4, c0 = xq * 64;
  const int bC1 = b * C1;
  const float BNS = 1.f / sqrtf(1.f + 1e-5f);

  if (t < 16) PSs[t] = pscale[b * NP + py * GW + xq * 16 + t];
  __syncthreads();
  const bool sel = PSs[t & 15] != 0.f;    // staging patch = t&15; skip x loads if ==0

  // staging coords (GEMM1)
  const int rr = (t >> 4) & 3, v4 = t & 15;
  const int n_lo72 = (32 * (rr >> 1) + v4) * 72;
  const int n_hi72 = n_lo72 + 16 * 72;
  const int kb0 = 4 * w + 2 * (rr & 1);
  const int kb1 = kb0 + 32;
  const size_t xoff0 = ((size_t)bC1 + w) * HW + (size_t)(r0 + rr) * WW + c0 + v4 * 4;
  const size_t xoff1 = xoff0 + (size_t)8 * HW;
  const int m_0 = t >> 3, k8_0 = t & 7;
  const int wi0 = m_0 * 1024 + k8_0 * 8;
  const int wi1 = (m_0 + 64) * 1024 + k8_0 * 8;
  const int wcw0 = m_0 * 72 + k8_0 * 8;
  const int wcw1 = (m_0 + 64) * 72 + k8_0 * 8;
  // mfma coords
  const int ut_off = (16 * wn + l15) * 72 + l4 * 8;
  const int wc_off = (64 * wm + l15) * 72 + l4 * 8;
  const int otc = 16 * wn + l15;
  // GEMM2 coords
  const int w2a = (t >> 3) * 136 + (t & 7) * 8;
  const int w2b = w2a + 64;
  const int w2s = (t >> 3) * 128 + (t & 7) * 8;
  const int g2_off = (32 * wm + l15) * 136 + l4 * 8;
  // store coords
  const int o_p = t & 15, o_rr = (t >> 4) & 3, o_cl = t >> 6;

  const float* xf = (const float*)xin;
  const unsigned short* xh = (const unsigned short*)xin;

  // named staging registers, zero-init (unselected lanes keep zeros)
  float4 Af0 = {0,0,0,0}, Af1 = {0,0,0,0}, Bf0 = {0,0,0,0}, Bf1 = {0,0,0,0};
  ushort4 Ah0 = {0,0,0,0}, Ah1 = {0,0,0,0}, Bh0 = {0,0,0,0}, Bh1 = {0,0,0,0};
  uint4 Aw0, Aw1, Bw0, Bw1;
  uint4 A2a, A2b, B2a, B2b;

  f32x4 acc10 = (f32x4){0.f,0.f,0.f,0.f};
  f32x4 acc11 = (f32x4){0.f,0.f,0.f,0.f};
  f32x4 acc12 = (f32x4){0.f,0.f,0.f,0.f};
  f32x4 acc13 = (f32x4){0.f,0.f,0.f,0.f};

  // ---- GEMM1: 16 K-chunks, LDS double-buffered, 1 barrier/chunk ----
  XLOAD(A, 0);
  XLOAD(B, 1);
  for (int cc2 = 0; cc2 < 8; ++cc2) {
    int cc = cc2 * 2;
    XWRITE(A, UT0, WC0);
    if (cc2 < 7) XLOAD(A, cc + 2);
    __syncthreads();
    G1_MFMA(UT0, WC0);
    XWRITE(B, UT1, WC1);
    if (cc2 < 7) XLOAD(B, cc + 3);
    __syncthreads();
    G1_MFMA(UT1, WC1);
  }

  // prefetch GEMM2 weight tiles 0,1 early (L2-resident)
  A2a = *(const uint4*)(W2b + w2s);
  A2b = *(const uint4*)(W2b + w2s + 64);
  B2a = *(const uint4*)(W2b + 8192 + w2s);
  B2b = *(const uint4*)(W2b + 8192 + w2s + 64);

  __syncthreads();               // all GEMM1 LDS reads done (O1 aliases WC)
  G1EPI(acc10, 0);
  G1EPI(acc11, 1);
  G1EPI(acc12, 2);
  G1EPI(acc13, 3);
  __syncthreads();

  // ---- depthwise 3x3 on 2x2 + BN + SiLU -> Y2T[n][h] bf16 ----
  {
    const int p = t & 15, hh = t >> 4;   // hh 0..31
#pragma unroll
    for (int s = 0; s < 4; ++s) {
      int h = hh + 32 * s;
      float i0 = O1[h * 68 + p];
      float i1 = O1[h * 68 + 16 + p];
      float i2 = O1[h * 68 + 32 + p];
      float i3 = O1[h * 68 + 48 + p];
      const float* kw = F + F_DWW + h * 9;
      float sd = F[F_DWG + h] * BNS, bd = F[F_DWB + h];
      float o00 = kw[4] * i0 + kw[5] * i1 + kw[7] * i2 + kw[8] * i3;
      float o01 = kw[3] * i0 + kw[4] * i1 + kw[6] * i2 + kw[7] * i3;
      float o10 = kw[1] * i0 + kw[2] * i1 + kw[4] * i2 + kw[5] * i3;
      float o11 = kw[0] * i0 + kw[1] * i1 + kw[3] * i2 + kw[4] * i3;
      Y2T[(0 * 16 + p) * 136 + h] = f2b(siluf(o00 * sd + bd));
      Y2T[(1 * 16 + p) * 136 + h] = f2b(siluf(o01 * sd + bd));
      Y2T[(2 * 16 + p) * 136 + h] = f2b(siluf(o10 * sd + bd));
      Y2T[(3 * 16 + p) * 136 + h] = f2b(siluf(o11 * sd + bd));
    }
  }
  __syncthreads();

  // ---- GEMM2: 16 M-tiles of 64, LDS double-buffered weights ----
  const int ybase = (16 * wn + l15) * 136 + l4 * 8;
  bf16x8 bq0 = *(const bf16x8*)&Y2T[ybase];
  bf16x8 bq1 = *(const bf16x8*)&Y2T[ybase + 32];
  bf16x8 bq2 = *(const bf16x8*)&Y2T[ybase + 64];
  bf16x8 bq3 = *(const bf16x8*)&Y2T[ybase + 96];

  for (int mtt = 0; mtt < 16; mtt += 2) {
    G2_STEP(A2, WC20, mtt);
    G2_STEP(B2, WC21, mtt + 1);
  }
}

extern "C" void kernel_launch(void* const* d_in, const int* in_sizes, int n_in,
                              void* d_out, int out_size, void* d_ws, size_t ws_size,
                              hipStream_t stream) {
  char* ws = (char*)d_ws;
  const void* x = d_in[0];
  k_detect<<<1, 256, 0, stream>>>((const unsigned short*)x, ws);
  k_prep<<<1104, 256, 0, stream>>>(d_in[1], d_in[2], d_in[3], d_in[4], d_in[5], d_in[6],
                                   d_in[7], d_in[8], d_in[9], d_in[10], d_in[11], d_in[12],
                                   d_in[13], d_in[14], ws);
  k_pool<<<18432, 256, 0, stream>>>(x, ws);
  k_mlp<<<288, 512, 0, stream>>>(ws);
  k_route<<<72, 256, 0, stream>>>(ws);
  k_expert<<<1152, 512, 0, stream>>>(x, d_out, ws);
}